// Round 18
// baseline (190.353 us; speedup 1.0000x reference)
//
#include <hip/hip_runtime.h>
#include <hip/hip_bf16.h>
#include <stdint.h>

#define B_   2
#define T_   2048
#define CEMB 2048
#define H_   16
#define HKV_ 4
#define D_   128

typedef __attribute__((ext_vector_type(8))) short bf16x8;    // 8 x bf16 (4 VGPR)
typedef __attribute__((ext_vector_type(4))) float f32x4;     // 16x16 MFMA acc
typedef __attribute__((ext_vector_type(16))) float f32x16;   // 32x32 MFMA acc

#if __has_builtin(__builtin_amdgcn_exp2f)
#define EXP2(x) __builtin_amdgcn_exp2f(x)
#else
#define EXP2(x) exp2f(x)
#endif

__device__ __forceinline__ unsigned short f2b(float f) {
  union { float f; unsigned u; } v; v.f = f;
  unsigned r = v.u + 0x7FFFu + ((v.u >> 16) & 1u);   // RNE
  return (unsigned short)(r >> 16);
}
__device__ __forceinline__ float b2f(unsigned short u) {
  union { unsigned u; float f; } v; v.u = ((unsigned)u) << 16; return v.f;
}
// pack 2 f32 -> 2 bf16 (RNE), single instruction; src0 -> low half
__device__ __forceinline__ unsigned cvtpk(float lo, float hi) {
  unsigned r;
  asm("v_cvt_pk_bf16_f32 %0, %1, %2" : "=v"(r) : "v"(lo), "v"(hi));
  return r;
}

// permlane32_swap: a' = [a_lo31 | b_lo31], b' = [a_hi31 | b_hi31]
#if __has_builtin(__builtin_amdgcn_permlane32_swap)
__device__ __forceinline__ void pl32(unsigned& a, unsigned& b) {
  auto r = __builtin_amdgcn_permlane32_swap(a, b, false, false);
  a = r[0]; b = r[1];
}
#else
__device__ __forceinline__ void pl32(unsigned& a, unsigned& b) {
  const bool hih = (threadIdx.x & 32) != 0;
  unsigned sa = __shfl_xor(a, 32), sb = __shfl_xor(b, 32);
  unsigned na = hih ? sb : a;
  unsigned nb = hih ? b : sa;
  a = na; b = nb;
}
#endif

// async global->LDS, 16B per lane; LDS dest = wave-uniform base + lane*16
__device__ __forceinline__ void gl16(const void* g, void* l) {
  __builtin_amdgcn_global_load_lds(
      (const __attribute__((address_space(1))) unsigned int*)g,
      (__attribute__((address_space(3))) unsigned int*)l, 16, 0, 0);
}

#define FENCE() asm volatile("" ::: "memory")

// ---------------- f32 -> bf16 convert, 5 ranges in ONE dispatch --------------
__global__ void cvt_multi(const float* __restrict__ s0, unsigned short* __restrict__ d0, int n0,
                          const float* __restrict__ s1, unsigned short* __restrict__ d1, int n1,
                          const float* __restrict__ s2, unsigned short* __restrict__ d2, int n2,
                          const float* __restrict__ s3, unsigned short* __restrict__ d3, int n3,
                          const float* __restrict__ s4, unsigned short* __restrict__ d4, int n4c) {
  const int stride = gridDim.x * blockDim.x;
  const int t0 = blockIdx.x * blockDim.x + threadIdx.x;
  auto run = [&](const float* __restrict__ s, unsigned short* __restrict__ d, int n) {
    for (int i = t0; i < n; i += stride) {
      float4 v = ((const float4*)s)[i];
      ushort4 o;
      o.x = f2b(v.x); o.y = f2b(v.y); o.z = f2b(v.z); o.w = f2b(v.w);
      ((ushort4*)d)[i] = o;
    }
  };
  run(s0, d0, n0); run(s1, d1, n1); run(s2, d2, n2);
  run(s3, d3, n3); run(s4, d4, n4c);
}

// ---------------- GEMM 256x192 (QKV), single-phase, full-grid ----------------
// (validated R15 structure, unchanged)
__global__ __launch_bounds__(512, 2)
void gemm_n192(const unsigned short* __restrict__ A,
               const unsigned short* __restrict__ W,
               unsigned short* __restrict__ Cmat, int M, int N, int K) {
  __shared__ alignas(16) unsigned short As[2][2][128][64];
  __shared__ alignas(16) unsigned short Bs[2][192][64];

  const int tid  = threadIdx.x;
  const int lane = tid & 63;
  const int w    = tid >> 6;         // wave 0..7
  const int wm   = w >> 1;           // M group: rows wm*64 .. +63
  const int wn   = w & 1;            // N group: cols wn*96 .. +95
  const int l16  = lane & 15, g4 = lane >> 4;
  const int srow = lane >> 3;
  const int schk = lane & 7;

  const int gx  = gridDim.x;         // N/192 = 16
  const int nwg = gx * gridDim.y;
  const int lin = blockIdx.y * gx + blockIdx.x;
  const int cpx = nwg >> 3;
  const int swz = (lin & 7) * cpx + (lin >> 3);
  const int m0 = (swz / gx) * 256;
  const int n0 = (swz % gx) * 192;

  const unsigned short* Ap = A + (size_t)m0 * K;
  const unsigned short* Wp = W + (size_t)n0 * K;
  const int nk = K >> 6;

  const int hA  = wm >> 1;           // this wave's A half
  const int ra0 = (wm & 1) * 64;     // row base within half

  f32x4 acc[4][6] = {};

  auto stA = [&](int ts, int h) {    // A half-tile: 128 rows x 64 k, 2 gl16
    const unsigned short* g = Ap + (size_t)(h * 128 + w * 8 + srow) * K
                                 + ts * 64 + ((schk ^ srow) << 3);
    unsigned short* l = &As[ts & 1][h][w * 8][0];
    gl16(g, l);
    gl16(g + (size_t)64 * K, l + 64 * 64);
  };
  auto stB = [&](int ts, int j) {    // B sub-tile j: 64 rows x 64 k, 1 gl16
    const unsigned short* g = Wp + (size_t)(j * 64 + w * 8 + srow) * K
                                 + ts * 64 + ((schk ^ srow) << 3);
    gl16(g, &Bs[ts & 1][j * 64 + w * 8][0]);
  };

  // prologue: stage tile0 fully (7 gl16/wave), drain, barrier
  stA(0, 0); stA(0, 1); stB(0, 0); stB(0, 1); stB(0, 2);
  asm volatile("s_waitcnt vmcnt(0)" ::: "memory");
  __builtin_amdgcn_s_barrier();
  FENCE();

  for (int t = 0; t < nk; ++t) {
    const int buf = t & 1;
    bf16x8 af[4][2], bfr[6][2];
    #pragma unroll
    for (int mi = 0; mi < 4; ++mi) {
      const int ar = ra0 + mi * 16 + l16;
      #pragma unroll
      for (int ks = 0; ks < 2; ++ks)
        af[mi][ks] = *(const bf16x8*)&As[buf][hA][ar][((ks * 4 + g4) ^ (l16 & 7)) << 3];
    }
    #pragma unroll
    for (int fc = 0; fc < 6; ++fc) {
      const int br = wn * 96 + fc * 16 + l16;
      #pragma unroll
      for (int ks = 0; ks < 2; ++ks)
        bfr[fc][ks] = *(const bf16x8*)&Bs[buf][br][((ks * 4 + g4) ^ (l16 & 7)) << 3];
    }
    if (t + 1 < nk) {
      stA(t + 1, 0); stA(t + 1, 1);
      stB(t + 1, 0); stB(t + 1, 1); stB(t + 1, 2);
    }
    __builtin_amdgcn_s_setprio(1);
    #pragma unroll
    for (int mi = 0; mi < 4; ++mi) {
      #pragma unroll
      for (int fc = 0; fc < 6; ++fc) {
        f32x4 a = acc[mi][fc];
        a = __builtin_amdgcn_mfma_f32_16x16x32_bf16(af[mi][0], bfr[fc][0], a, 0, 0, 0);
        a = __builtin_amdgcn_mfma_f32_16x16x32_bf16(af[mi][1], bfr[fc][1], a, 0, 0, 0);
        acc[mi][fc] = a;
      }
    }
    __builtin_amdgcn_s_setprio(0);
    asm volatile("s_waitcnt vmcnt(0)" ::: "memory");   // t+1 staged (drained under MFMA)
    __builtin_amdgcn_s_barrier();
    FENCE();
  }

  // epilogue: bf16 out
  #pragma unroll
  for (int mi = 0; mi < 4; ++mi) {
    #pragma unroll
    for (int fc = 0; fc < 6; ++fc) {
      const int row = m0 + wm * 64 + mi * 16 + g4 * 4;
      const int col = n0 + wn * 96 + fc * 16 + l16;
      #pragma unroll
      for (int r = 0; r < 4; ++r)
        Cmat[(size_t)(row + r) * N + col] = f2b(acc[mi][fc][r]);
    }
  }
}

// ---------------- GEMM 256x128 (out-proj), single-phase, TRIPLE buffer -------
// Counted-vmcnt pipeline: stage tile t+2 during tile t; end-of-tile gate
// vmcnt(6) leaves exactly t+2's 6 issues in flight while draining t+1's
// (RAW: tile t staged during t-2, drained by end-of-(t-1) gate; WAR: buf
// (t+2)%3 last read during tile t-1, fenced by its end barrier).  The 48 KB
// stage drain moves off the critical path (was serialized after MFMA every
// K-tile with the 2-buffer vmcnt(0) gate).  LDS 144 KB.
__global__ __launch_bounds__(512)
void gemm_n128(const unsigned short* __restrict__ A,
               const unsigned short* __restrict__ W,
               float* __restrict__ Cmat, int M, int N, int K) {
  __shared__ alignas(16) unsigned short As[3][2][128][64];   // 96 KB
  __shared__ alignas(16) unsigned short Bs[3][2][64][64];    // 48 KB

  const int tid  = threadIdx.x;
  const int lane = tid & 63;
  const int w    = tid >> 6;         // wave 0..7
  const int wm   = w >> 1;           // M group: rows wm*64 .. +63
  const int wn   = w & 1;            // N group: cols wn*64 .. +63
  const int l16  = lane & 15, g4 = lane >> 4;
  const int srow = lane >> 3;
  const int schk = lane & 7;

  const int gx  = gridDim.x;         // N/128
  const int nwg = gx * gridDim.y;
  const int lin = blockIdx.y * gx + blockIdx.x;
  const int cpx = nwg >> 3;
  const int swz = (lin & 7) * cpx + (lin >> 3);
  const int m0 = (swz / gx) * 256;
  const int n0 = (swz % gx) * 128;

  const unsigned short* Ap = A + (size_t)m0 * K;
  const unsigned short* Wp = W + (size_t)n0 * K;
  const int nk = K >> 6;

  const int hA  = wm >> 1;
  const int ra0 = (wm & 1) * 64;

  f32x4 acc[4][4] = {};

  auto stA = [&](int ts, int h) {    // A half-tile: 128 rows x 64 k, 2 gl16
    const int buf = ts % 3;
    const unsigned short* g = Ap + (size_t)(h * 128 + w * 8 + srow) * K
                                 + ts * 64 + ((schk ^ srow) << 3);
    unsigned short* l = &As[buf][h][w * 8][0];
    gl16(g, l);
    gl16(g + (size_t)64 * K, l + 64 * 64);
  };
  auto stB = [&](int ts, int h) {    // B half-tile: 64 rows x 64 k, 1 gl16
    const int buf = ts % 3;
    const unsigned short* g = Wp + (size_t)(h * 64 + w * 8 + srow) * K
                                 + ts * 64 + ((schk ^ srow) << 3);
    gl16(g, &Bs[buf][h][w * 8][0]);
  };
  auto stage = [&](int ts) {         // full tile: 6 gl16/wave
    stA(ts, 0); stA(ts, 1); stB(ts, 0); stB(ts, 1);
  };

  // prologue: stage tiles 0 and 1 (12 gl16/wave); drain tile0 (6 remain)
  stage(0); stage(1);
  asm volatile("s_waitcnt vmcnt(6)" ::: "memory");
  __builtin_amdgcn_s_barrier();
  FENCE();

  for (int t = 0; t < nk; ++t) {
    const int buf = t % 3;
    bf16x8 af[4][2], bfr[4][2];
    #pragma unroll
    for (int mi = 0; mi < 4; ++mi) {
      const int ar = ra0 + mi * 16 + l16;
      #pragma unroll
      for (int ks = 0; ks < 2; ++ks)
        af[mi][ks] = *(const bf16x8*)&As[buf][hA][ar][((ks * 4 + g4) ^ (l16 & 7)) << 3];
    }
    #pragma unroll
    for (int fc = 0; fc < 4; ++fc) {
      const int br = wn * 64 + fc * 16 + l16;   // 0..127 across halves
      const int hb = br >> 6, rb = br & 63;
      #pragma unroll
      for (int ks = 0; ks < 2; ++ks)
        bfr[fc][ks] = *(const bf16x8*)&Bs[buf][hb][rb][((ks * 4 + g4) ^ (l16 & 7)) << 3];
    }
    if (t + 2 < nk) stage(t + 2);
    __builtin_amdgcn_s_setprio(1);
    #pragma unroll
    for (int mi = 0; mi < 4; ++mi) {
      #pragma unroll
      for (int fc = 0; fc < 4; ++fc) {
        f32x4 a = acc[mi][fc];
        a = __builtin_amdgcn_mfma_f32_16x16x32_bf16(af[mi][0], bfr[fc][0], a, 0, 0, 0);
        a = __builtin_amdgcn_mfma_f32_16x16x32_bf16(af[mi][1], bfr[fc][1], a, 0, 0, 0);
        acc[mi][fc] = a;
      }
    }
    __builtin_amdgcn_s_setprio(0);
    // gate: drain tile t+1's stages (issued during t-1); t+2's 6 stay in flight
    if (t + 2 < nk) asm volatile("s_waitcnt vmcnt(6)" ::: "memory");
    else            asm volatile("s_waitcnt vmcnt(0)" ::: "memory");
    __builtin_amdgcn_s_barrier();
    FENCE();
  }

  // epilogue: f32 out
  #pragma unroll
  for (int mi = 0; mi < 4; ++mi) {
    #pragma unroll
    for (int fc = 0; fc < 4; ++fc) {
      const int row = m0 + wm * 64 + mi * 16 + g4 * 4;
      const int col = n0 + wn * 64 + fc * 16 + l16;
      #pragma unroll
      for (int r = 0; r < 4; ++r)
        Cmat[(size_t)(row + r) * N + col] = acc[mi][fc][r];
    }
  }
}

// ---------------- fused RoPE + RMSNorm (bf16 in) + [B,H,T,D] bf16 out --------
__global__ __launch_bounds__(128)
void rope_norm(const unsigned short* __restrict__ X, int rstride,
               const float* __restrict__ Cos, const float* __restrict__ Sin,
               unsigned short* __restrict__ Out, int Hn, float out_scale) {
  const int idx = blockIdx.x;
  const int h  = idx % Hn;
  const int bt = idx / Hn;
  const int t  = bt & (T_ - 1);
  const int b  = bt >> 11;
  const int d  = threadIdx.x;        // 0..127
  const unsigned short* src = X + (size_t)bt * rstride + h * D_;
  float y;
  if (d < 64) {
    float x1 = b2f(src[d]), x2 = b2f(src[d + 64]);
    float c = Cos[t * 64 + d], s = Sin[t * 64 + d];
    y = x1 * c + x2 * s;
  } else {
    int dd = d - 64;
    float x1 = b2f(src[dd]), x2 = b2f(src[d]);
    float c = Cos[t * 64 + dd], s = Sin[t * 64 + dd];
    y = -x1 * s + x2 * c;
  }
  float ss = y * y;
  #pragma unroll
  for (int m = 32; m; m >>= 1) ss += __shfl_xor(ss, m);
  __shared__ float red[2];
  if ((d & 63) == 0) red[d >> 6] = ss;
  __syncthreads();
  const float tot  = red[0] + red[1];
  const float rinv = rsqrtf(tot * (1.0f / 128.0f) + 1.1920929e-7f) * out_scale;
  Out[(((size_t)b * Hn + h) * T_ + t) * D_ + d] = f2b(y * rinv);
}

// ---------------- V: [B,T,*,D] bf16 (strided) -> [B,HKV,D,T] bf16 ------------
__global__ __launch_bounds__(256)
void vtrans(const unsigned short* __restrict__ Vf, int rstride,
            unsigned short* __restrict__ Vt) {
  __shared__ float tile[32][65];
  const int t0 = blockIdx.x * 64;
  const int d0 = blockIdx.y * 32;
  const int bh = blockIdx.z;
  const int b = bh >> 2, hk = bh & 3;
  const int tid = threadIdx.x;
  {
    const int di = tid & 31, ts = tid >> 5;
    #pragma unroll
    for (int i = 0; i < 8; ++i) {
      int tt = ts + i * 8;
      tile[di][tt] = b2f(Vf[(size_t)(b * T_ + t0 + tt) * rstride + hk * D_ + d0 + di]);
    }
  }
  __syncthreads();
  {
    const int ti = tid & 63, ds = tid >> 6;
    #pragma unroll
    for (int i = 0; i < 8; ++i) {
      int dd = ds * 8 + i;
      Vt[((size_t)bh * D_ + d0 + dd) * T_ + t0 + ti] = f2b(tile[dd][ti]);
    }
  }
}

// ---------------- flash attention, causal, 8-wave / KVB=128 ------------------
// R15-validated version (59.4 us): split grid (32 bh x 16), complementary qt
// map, &15 swizzle (conflict-free), in-register P, fixed-shift softmax.
#define KVB 128

__global__ __launch_bounds__(512)
void attn_kernel(const unsigned short* __restrict__ Qn,
                 const unsigned short* __restrict__ Kn,
                 const unsigned short* __restrict__ Vt,
                 unsigned short* __restrict__ Yb) {
  __shared__ alignas(16) unsigned short Ks[2][KVB][D_];   // [key][chunk^(key&15)]
  __shared__ alignas(16) unsigned short Vs[2][D_][KVB];   // V^T [d][chunk^(d&15)]

  const int tid = threadIdx.x;
  const int lane = tid & 63;
  const int w = tid >> 6;                 // 0..7
  const int wq  = w & 3;                  // q-row group
  const int kvg = w >> 2;                 // kv key group (0: keys 0-63, 1: 64-127)
  const int l31 = lane & 31;
  const int hi  = lane >> 5;
  const int bh = blockIdx.x;              // bh-major: XCD KV working set = 4MB
  const int by = blockIdx.y;
  const int qt = (by < 8) ? by : 23 - by; // complementary halves
  const int b = bh >> 4, h = bh & 15;
  const int hk = h >> 2;                  // GQA: 4 q-heads per kv-head

  const unsigned short* kp = Kn + ((size_t)(b * HKV_ + hk) * T_) * D_;
  const unsigned short* vp = Vt + ((size_t)(b * HKV_ + hk) * D_) * T_;

  // staging lane decomposition: 4 rows (1KB) per gl16, 16 chunks/row
  const int r4 = lane >> 4, c16 = lane & 15;

  const int t0 = qt * 128;
  const int qrow0 = t0 + wq * 32;
  const int qmax = qrow0 + 31;
  const int nt = qt + 1;
  const int qglob = qrow0 + l31;

  // Q fragments: B-operand, col=q=lane&31, k-chunk = hi*8
  const unsigned short* qp = Qn + ((size_t)bh * T_ + qrow0) * D_;
  bf16x8 qf[8];
  #pragma unroll
  for (int ds = 0; ds < 8; ++ds)
    qf[ds] = *(const bf16x8*)(qp + (size_t)l31 * D_ + ds * 16 + hi * 8);

  f32x16 o[4] = {};        // o[db]: O[q=crow(r,hi)][d = db*32 + l31] (group partial)
  float l_lane = 0.f;      // per-lane partial l for q = l31 over this kv group

  auto stage = [&](int tt) {
    const int buf = tt & 1;
    const int kv = tt * KVB;
    #pragma unroll
    for (int j = 0; j < 4; ++j) {
      const int row = w * 16 + j * 4 + r4;
      const int cg = c16 ^ (row & 15);
      gl16(kp + (size_t)(kv + row) * D_ + cg * 8, &Ks[buf][w * 16 + j * 4][0]);
    }
    #pragma unroll
    for (int j = 0; j < 4; ++j) {
      const int row = w * 16 + j * 4 + r4;   // d row
      const int cg = c16 ^ (row & 15);
      gl16(vp + (size_t)row * T_ + kv + cg * 8, &Vs[buf][w * 16 + j * 4][0]);
    }
  };

  stage(0);   // prologue

  union PAu { unsigned u[4]; bf16x8 v; };

  for (int t = 0; t < nt; ++t) {
    __syncthreads();          // drains vmcnt(0): buf[t&1] staged; prev reads done
    if (t + 1 < nt) stage(t + 1);
    const int kbase = t * KVB + kvg * 64;   // this wave's key base
    if (kbase <= qmax) {
      const unsigned short (*kb)[D_]  = Ks[t & 1];
      const unsigned short (*vbp)[KVB] = Vs[t & 1];
      // ---- QK^T swapped: mfma32(K_frag, Q_frag) over this wave's 64 keys ----
      f32x16 s0 = {}, s1 = {};
      __builtin_amdgcn_s_setprio(1);
      #pragma unroll
      for (int ds = 0; ds < 8; ++ds) {
        const int key0 = kvg * 64 + l31;
        const int key1 = kvg * 64 + 32 + l31;
        bf16x8 k0 = *(const bf16x8*)&kb[key0][(((ds * 2 + hi) ^ (key0 & 15)) << 3)];
        bf16x8 k1 = *(const bf16x8*)&kb[key1][(((ds * 2 + hi) ^ (key1 & 15)) << 3)];
        s0 = __builtin_amdgcn_mfma_f32_32x32x16_bf16(k0, qf[ds], s0, 0, 0, 0);
        s1 = __builtin_amdgcn_mfma_f32_32x32x16_bf16(k1, qf[ds], s1, 0, 0, 0);
      }
      __builtin_amdgcn_s_setprio(0);
      // ---- softmax (fixed-shift, exp2 domain; RMSNorm bound |arg|<=16.33) ----
      const bool need_mask = (kbase + 63 > qrow0);
      float e0[16], e1[16];
      float ls = 0.f;
      #pragma unroll
      for (int r = 0; r < 16; ++r) {
        const int crow = (r & 3) + 8 * (r >> 2) + 4 * hi;
        float v0 = EXP2(s0[r]);
        float v1 = EXP2(s1[r]);
        if (need_mask) {
          v0 = (kbase + crow      <= qglob) ? v0 : 0.f;
          v1 = (kbase + 32 + crow <= qglob) ? v1 : 0.f;
        }
        e0[r] = v0; e1[r] = v1;
        ls += v0 + v1;
      }
      l_lane += ls;
      // ---- build PV A-fragments in-register (cvt_pk + permlane32_swap) ----
      PAu pa[4];
      {
        unsigned a0 = cvtpk(e0[0],  e0[1]),  a1 = cvtpk(e0[2],  e0[3]);
        unsigned b0 = cvtpk(e0[4],  e0[5]),  b1 = cvtpk(e0[6],  e0[7]);
        unsigned c0 = cvtpk(e0[8],  e0[9]),  c1 = cvtpk(e0[10], e0[11]);
        unsigned d0 = cvtpk(e0[12], e0[13]), d1 = cvtpk(e0[14], e0[15]);
        pl32(a0, b0); pl32(a1, b1); pl32(c0, d0); pl32(c1, d1);
        pa[0].u[0] = a0; pa[0].u[1] = a1; pa[0].u[2] = b0; pa[0].u[3] = b1;
        pa[1].u[0] = c0; pa[1].u[1] = c1; pa[1].u[2] = d0; pa[1].u[3] = d1;
      }
      {
        unsigned a0 = cvtpk(e1[0],  e1[1]),  a1 = cvtpk(e1[2],  e1[3]);
        unsigned b0 = cvtpk(e1[4],  e1[5]),  b1 = cvtpk(e1[6],  e1[7]);
        unsigned c0 = cvtpk(e1[8],  e1[9]),  c1 = cvtpk(e1[10], e1[11]);
        unsigned d0 = cvtpk(e1[12], e1[13]), d1 = cvtpk(e1[14], e1[15]);
        pl32(a0, b0); pl32(a1, b1); pl32(c0, d0); pl32(c1, d1);
        pa[2].u[0] = a0; pa[2].u[1] = a1; pa[2].u[2] = b0; pa[2].u[3] = b1;
        pa[3].u[0] = c0; pa[3].u[1] = c1; pa[3].u[2] = d0; pa[3].u[3] = d1;
      }
      // ---- PV: O[q][d] += P[q][key] * V[key][d], V as B-frag from V^T ----
      __builtin_amdgcn_s_setprio(1);
      #pragma unroll
      for (int ks = 0; ks < 4; ++ks) {
        #pragma unroll
        for (int db = 0; db < 4; ++db) {
          const int d = db * 32 + l31;
          const int c = (kvg * 8 + ks * 2 + hi) ^ (d & 15);
          bf16x8 vf = *(const bf16x8*)&vbp[d][c << 3];
          o[db] = __builtin_amdgcn_mfma_f32_32x32x16_bf16(pa[ks].v, vf, o[db], 0, 0, 0);
        }
      }
      __builtin_amdgcn_s_setprio(0);
    }
  }

  // ---- epilogue: combine kv-group partials via LDS (reuse K/V buffers) ----
  const float lfull = l_lane + __shfl_xor(l_lane, 32);  // this group's l for q=l31
  __syncthreads();                       // all waves done with K/V LDS
  float* obuf = (float*)&Ks[0][0][0];    // 64 KB: 4 waves x 4096 floats
  float* lbuf = (float*)&Vs[0][0][0];
  if (w >= 4) {
    const int base = (w - 4) * 4096;
    #pragma unroll
    for (int r = 0; r < 16; ++r)
      #pragma unroll
      for (int db = 0; db < 4; ++db)
        obuf[base + (r * 4 + db) * 64 + lane] = o[db][r];
    if (hi == 0) lbuf[(w - 4) * 32 + l31] = lfull;
  }
  __syncthreads();
  if (w < 4) {
    const int base = w * 4096;
    const float ltot = lfull + lbuf[w * 32 + l31];
    const float invq = 1.0f / ltot;
    #pragma unroll
    for (int r = 0; r < 16; ++r) {
      const int crow = (r & 3) + 8 * (r >> 2) + 4 * hi;
      const float inv = __shfl(invq, crow);
      unsigned short* yrow = Yb + ((size_t)(b * T_ + qrow0 + crow) * CEMB) + h * D_;
      #pragma unroll
      for (int db = 0; db < 4; ++db)
        yrow[db * 32 + l31] = f2b((o[db][r] + obuf[base + (r * 4 + db) * 64 + lane]) * inv);
    }
  }
}

// ---------------------------------------------------------------------------
extern "C" void kernel_launch(void* const* d_in, const int* in_sizes, int n_in,
                              void* d_out, int out_size, void* d_ws, size_t ws_size,
                              hipStream_t stream) {
  const float* x    = (const float*)d_in[0];
  const float* cosp = (const float*)d_in[1];
  const float* sinp = (const float*)d_in[2];
  const float* Wq   = (const float*)d_in[3];
  const float* Wk   = (const float*)d_in[4];
  const float* Wv   = (const float*)d_in[5];
  const float* Wo   = (const float*)d_in[6];
  float* out = (float*)d_out;

  char* ws = (char*)d_ws;
  size_t off = 0;
  auto alloc = [&](size_t bytes) {
    void* p = ws + off;
    off += (bytes + 255) & ~(size_t)255;
    return p;
  };
  const size_t MT = (size_t)B_ * T_;  // 4096
  const int NQKV = 3072;              // 2048 q + 512 k + 512 v
  unsigned short* xb    = (unsigned short*)alloc(MT * CEMB * 2);
  unsigned short* wqkvb = (unsigned short*)alloc((size_t)NQKV * 2048 * 2);
  unsigned short* wob   = (unsigned short*)alloc((size_t)2048 * 2048 * 2);
  unsigned short* qkvb  = (unsigned short*)alloc(MT * NQKV * 2);
  unsigned short* qn    = (unsigned short*)alloc((size_t)B_ * H_ * T_ * D_ * 2);
  unsigned short* kn    = (unsigned short*)alloc((size_t)B_ * HKV_ * T_ * D_ * 2);
  unsigned short* vt    = (unsigned short*)alloc((size_t)B_ * HKV_ * D_ * T_ * 2);
  unsigned short* yb    = (unsigned short*)alloc(MT * CEMB * 2);

  // all 5 f32->bf16 conversions in ONE dispatch
  cvt_multi<<<2048, 256, 0, stream>>>(
      x,  xb,                  (int)(MT * CEMB / 4),
      Wq, wqkvb,               2048 * 2048 / 4,
      Wk, wqkvb + 2048 * 2048, 512 * 2048 / 4,
      Wv, wqkvb + 2560 * 2048, 512 * 2048 / 4,
      Wo, wob,                 1024 * 4096 / 4);

  // fused QKV projection: [4096][3072] bf16  (grid 16x16 = 256 blocks, full)
  gemm_n192<<<dim3(NQKV / 192, 4096 / 256), 512, 0, stream>>>(xb, wqkvb, qkvb, 4096, NQKV, 2048);

  // RoPE + RMSNorm; Q gets (1/sqrt(D))*log2(e) folded (softmax in exp2 domain)
  rope_norm<<<4096 * H_,   128, 0, stream>>>(qkvb,        NQKV, cosp, sinp, qn, H_,   0.1275174324f);
  rope_norm<<<4096 * HKV_, 128, 0, stream>>>(qkvb + 2048, NQKV, cosp, sinp, kn, HKV_, 1.0f);
  vtrans<<<dim3(T_ / 64, D_ / 32, B_ * HKV_), 256, 0, stream>>>(qkvb + 2560, NQKV, vt);

  // causal flash attention: split grid (32 x 16), complementary qt map
  attn_kernel<<<dim3(B_ * H_, 16), 512, 0, stream>>>(qn, kn, vt, yb);

  // output projection -> f32 d_out  (grid 16x16 = 256 blocks, full machine)
  gemm_n128<<<dim3(2048 / 128, 4096 / 256), 512, 0, stream>>>(yb, wob, out, 4096, 2048, 2048);
}

// Round 19
// 187.336 us; speedup vs baseline: 1.0161x; 1.0161x over previous
//
#include <hip/hip_runtime.h>
#include <hip/hip_bf16.h>
#include <stdint.h>

#define B_   2
#define T_   2048
#define CEMB 2048
#define H_   16
#define HKV_ 4
#define D_   128

typedef __attribute__((ext_vector_type(8))) short bf16x8;    // 8 x bf16 (4 VGPR)
typedef __attribute__((ext_vector_type(4))) float f32x4;     // 16x16 MFMA acc
typedef __attribute__((ext_vector_type(16))) float f32x16;   // 32x32 MFMA acc

#if __has_builtin(__builtin_amdgcn_exp2f)
#define EXP2(x) __builtin_amdgcn_exp2f(x)
#else
#define EXP2(x) exp2f(x)
#endif

__device__ __forceinline__ unsigned short f2b(float f) {
  union { float f; unsigned u; } v; v.f = f;
  unsigned r = v.u + 0x7FFFu + ((v.u >> 16) & 1u);   // RNE
  return (unsigned short)(r >> 16);
}
__device__ __forceinline__ float b2f(unsigned short u) {
  union { unsigned u; float f; } v; v.u = ((unsigned)u) << 16; return v.f;
}
// pack 2 f32 -> 2 bf16 (RNE), single instruction; src0 -> low half
__device__ __forceinline__ unsigned cvtpk(float lo, float hi) {
  unsigned r;
  asm("v_cvt_pk_bf16_f32 %0, %1, %2" : "=v"(r) : "v"(lo), "v"(hi));
  return r;
}

// permlane32_swap: a' = [a_lo31 | b_lo31], b' = [a_hi31 | b_hi31]
#if __has_builtin(__builtin_amdgcn_permlane32_swap)
__device__ __forceinline__ void pl32(unsigned& a, unsigned& b) {
  auto r = __builtin_amdgcn_permlane32_swap(a, b, false, false);
  a = r[0]; b = r[1];
}
#else
__device__ __forceinline__ void pl32(unsigned& a, unsigned& b) {
  const bool hih = (threadIdx.x & 32) != 0;
  unsigned sa = __shfl_xor(a, 32), sb = __shfl_xor(b, 32);
  unsigned na = hih ? sb : a;
  unsigned nb = hih ? b : sa;
  a = na; b = nb;
}
#endif

// async global->LDS, 16B per lane; LDS dest = wave-uniform base + lane*16
__device__ __forceinline__ void gl16(const void* g, void* l) {
  __builtin_amdgcn_global_load_lds(
      (const __attribute__((address_space(1))) unsigned int*)g,
      (__attribute__((address_space(3))) unsigned int*)l, 16, 0, 0);
}

#define FENCE() asm volatile("" ::: "memory")

// ---------------- f32 -> bf16 convert, 5 ranges in ONE dispatch --------------
__global__ void cvt_multi(const float* __restrict__ s0, unsigned short* __restrict__ d0, int n0,
                          const float* __restrict__ s1, unsigned short* __restrict__ d1, int n1,
                          const float* __restrict__ s2, unsigned short* __restrict__ d2, int n2,
                          const float* __restrict__ s3, unsigned short* __restrict__ d3, int n3,
                          const float* __restrict__ s4, unsigned short* __restrict__ d4, int n4c) {
  const int stride = gridDim.x * blockDim.x;
  const int t0 = blockIdx.x * blockDim.x + threadIdx.x;
  auto run = [&](const float* __restrict__ s, unsigned short* __restrict__ d, int n) {
    for (int i = t0; i < n; i += stride) {
      float4 v = ((const float4*)s)[i];
      ushort4 o;
      o.x = f2b(v.x); o.y = f2b(v.y); o.z = f2b(v.z); o.w = f2b(v.w);
      ((ushort4*)d)[i] = o;
    }
  };
  run(s0, d0, n0); run(s1, d1, n1); run(s2, d2, n2);
  run(s3, d3, n3); run(s4, d4, n4c);
}

// ---------------- GEMM 256x192 (QKV), single-phase, full-grid ----------------
// (validated R15 structure, unchanged)
__global__ __launch_bounds__(512, 2)
void gemm_n192(const unsigned short* __restrict__ A,
               const unsigned short* __restrict__ W,
               unsigned short* __restrict__ Cmat, int M, int N, int K) {
  __shared__ alignas(16) unsigned short As[2][2][128][64];
  __shared__ alignas(16) unsigned short Bs[2][192][64];

  const int tid  = threadIdx.x;
  const int lane = tid & 63;
  const int w    = tid >> 6;         // wave 0..7
  const int wm   = w >> 1;           // M group: rows wm*64 .. +63
  const int wn   = w & 1;            // N group: cols wn*96 .. +95
  const int l16  = lane & 15, g4 = lane >> 4;
  const int srow = lane >> 3;
  const int schk = lane & 7;

  const int gx  = gridDim.x;         // N/192 = 16
  const int nwg = gx * gridDim.y;
  const int lin = blockIdx.y * gx + blockIdx.x;
  const int cpx = nwg >> 3;
  const int swz = (lin & 7) * cpx + (lin >> 3);
  const int m0 = (swz / gx) * 256;
  const int n0 = (swz % gx) * 192;

  const unsigned short* Ap = A + (size_t)m0 * K;
  const unsigned short* Wp = W + (size_t)n0 * K;
  const int nk = K >> 6;

  const int hA  = wm >> 1;           // this wave's A half
  const int ra0 = (wm & 1) * 64;     // row base within half

  f32x4 acc[4][6] = {};

  auto stA = [&](int ts, int h) {    // A half-tile: 128 rows x 64 k, 2 gl16
    const unsigned short* g = Ap + (size_t)(h * 128 + w * 8 + srow) * K
                                 + ts * 64 + ((schk ^ srow) << 3);
    unsigned short* l = &As[ts & 1][h][w * 8][0];
    gl16(g, l);
    gl16(g + (size_t)64 * K, l + 64 * 64);
  };
  auto stB = [&](int ts, int j) {    // B sub-tile j: 64 rows x 64 k, 1 gl16
    const unsigned short* g = Wp + (size_t)(j * 64 + w * 8 + srow) * K
                                 + ts * 64 + ((schk ^ srow) << 3);
    gl16(g, &Bs[ts & 1][j * 64 + w * 8][0]);
  };

  // prologue: stage tile0 fully (7 gl16/wave), drain, barrier
  stA(0, 0); stA(0, 1); stB(0, 0); stB(0, 1); stB(0, 2);
  asm volatile("s_waitcnt vmcnt(0)" ::: "memory");
  __builtin_amdgcn_s_barrier();
  FENCE();

  for (int t = 0; t < nk; ++t) {
    const int buf = t & 1;
    bf16x8 af[4][2], bfr[6][2];
    #pragma unroll
    for (int mi = 0; mi < 4; ++mi) {
      const int ar = ra0 + mi * 16 + l16;
      #pragma unroll
      for (int ks = 0; ks < 2; ++ks)
        af[mi][ks] = *(const bf16x8*)&As[buf][hA][ar][((ks * 4 + g4) ^ (l16 & 7)) << 3];
    }
    #pragma unroll
    for (int fc = 0; fc < 6; ++fc) {
      const int br = wn * 96 + fc * 16 + l16;
      #pragma unroll
      for (int ks = 0; ks < 2; ++ks)
        bfr[fc][ks] = *(const bf16x8*)&Bs[buf][br][((ks * 4 + g4) ^ (l16 & 7)) << 3];
    }
    if (t + 1 < nk) {
      stA(t + 1, 0); stA(t + 1, 1);
      stB(t + 1, 0); stB(t + 1, 1); stB(t + 1, 2);
    }
    __builtin_amdgcn_s_setprio(1);
    #pragma unroll
    for (int mi = 0; mi < 4; ++mi) {
      #pragma unroll
      for (int fc = 0; fc < 6; ++fc) {
        f32x4 a = acc[mi][fc];
        a = __builtin_amdgcn_mfma_f32_16x16x32_bf16(af[mi][0], bfr[fc][0], a, 0, 0, 0);
        a = __builtin_amdgcn_mfma_f32_16x16x32_bf16(af[mi][1], bfr[fc][1], a, 0, 0, 0);
        acc[mi][fc] = a;
      }
    }
    __builtin_amdgcn_s_setprio(0);
    asm volatile("s_waitcnt vmcnt(0)" ::: "memory");   // t+1 staged (drained under MFMA)
    __builtin_amdgcn_s_barrier();
    FENCE();
  }

  // epilogue: bf16 out
  #pragma unroll
  for (int mi = 0; mi < 4; ++mi) {
    #pragma unroll
    for (int fc = 0; fc < 6; ++fc) {
      const int row = m0 + wm * 64 + mi * 16 + g4 * 4;
      const int col = n0 + wn * 96 + fc * 16 + l16;
      #pragma unroll
      for (int r = 0; r < 4; ++r)
        Cmat[(size_t)(row + r) * N + col] = f2b(acc[mi][fc][r]);
    }
  }
}

// ---------------- GEMM 256x128 (out-proj), single-phase, full-grid -----------
// (validated R15/R17 2-buffer structure, restored after R18 triple-buffer null)
__global__ __launch_bounds__(512, 2)
void gemm_n128(const unsigned short* __restrict__ A,
               const unsigned short* __restrict__ W,
               float* __restrict__ Cmat, int M, int N, int K) {
  __shared__ alignas(16) unsigned short As[2][2][128][64];
  __shared__ alignas(16) unsigned short Bs[2][2][64][64];

  const int tid  = threadIdx.x;
  const int lane = tid & 63;
  const int w    = tid >> 6;         // wave 0..7
  const int wm   = w >> 1;           // M group: rows wm*64 .. +63
  const int wn   = w & 1;            // N group: cols wn*64 .. +63
  const int l16  = lane & 15, g4 = lane >> 4;
  const int srow = lane >> 3;
  const int schk = lane & 7;

  const int gx  = gridDim.x;         // N/128
  const int nwg = gx * gridDim.y;
  const int lin = blockIdx.y * gx + blockIdx.x;
  const int cpx = nwg >> 3;
  const int swz = (lin & 7) * cpx + (lin >> 3);
  const int m0 = (swz / gx) * 256;
  const int n0 = (swz % gx) * 128;

  const unsigned short* Ap = A + (size_t)m0 * K;
  const unsigned short* Wp = W + (size_t)n0 * K;
  const int nk = K >> 6;

  const int hA  = wm >> 1;
  const int ra0 = (wm & 1) * 64;

  f32x4 acc[4][4] = {};

  auto stA = [&](int ts, int h) {    // A half-tile: 128 rows x 64 k, 2 gl16
    const unsigned short* g = Ap + (size_t)(h * 128 + w * 8 + srow) * K
                                 + ts * 64 + ((schk ^ srow) << 3);
    unsigned short* l = &As[ts & 1][h][w * 8][0];
    gl16(g, l);
    gl16(g + (size_t)64 * K, l + 64 * 64);
  };
  auto stB = [&](int ts, int h) {    // B half-tile: 64 rows x 64 k, 1 gl16
    const unsigned short* g = Wp + (size_t)(h * 64 + w * 8 + srow) * K
                                 + ts * 64 + ((schk ^ srow) << 3);
    gl16(g, &Bs[ts & 1][h][w * 8][0]);
  };

  // prologue
  stA(0, 0); stA(0, 1); stB(0, 0); stB(0, 1);
  asm volatile("s_waitcnt vmcnt(0)" ::: "memory");
  __builtin_amdgcn_s_barrier();
  FENCE();

  for (int t = 0; t < nk; ++t) {
    const int buf = t & 1;
    bf16x8 af[4][2], bfr[4][2];
    #pragma unroll
    for (int mi = 0; mi < 4; ++mi) {
      const int ar = ra0 + mi * 16 + l16;
      #pragma unroll
      for (int ks = 0; ks < 2; ++ks)
        af[mi][ks] = *(const bf16x8*)&As[buf][hA][ar][((ks * 4 + g4) ^ (l16 & 7)) << 3];
    }
    #pragma unroll
    for (int fc = 0; fc < 4; ++fc) {
      const int br = wn * 64 + fc * 16 + l16;   // 0..127 across halves
      const int hb = br >> 6, rb = br & 63;
      #pragma unroll
      for (int ks = 0; ks < 2; ++ks)
        bfr[fc][ks] = *(const bf16x8*)&Bs[buf][hb][rb][((ks * 4 + g4) ^ (l16 & 7)) << 3];
    }
    if (t + 1 < nk) {
      stA(t + 1, 0); stA(t + 1, 1);
      stB(t + 1, 0); stB(t + 1, 1);
    }
    __builtin_amdgcn_s_setprio(1);
    #pragma unroll
    for (int mi = 0; mi < 4; ++mi) {
      #pragma unroll
      for (int fc = 0; fc < 4; ++fc) {
        f32x4 a = acc[mi][fc];
        a = __builtin_amdgcn_mfma_f32_16x16x32_bf16(af[mi][0], bfr[fc][0], a, 0, 0, 0);
        a = __builtin_amdgcn_mfma_f32_16x16x32_bf16(af[mi][1], bfr[fc][1], a, 0, 0, 0);
        acc[mi][fc] = a;
      }
    }
    __builtin_amdgcn_s_setprio(0);
    asm volatile("s_waitcnt vmcnt(0)" ::: "memory");
    __builtin_amdgcn_s_barrier();
    FENCE();
  }

  // epilogue: f32 out
  #pragma unroll
  for (int mi = 0; mi < 4; ++mi) {
    #pragma unroll
    for (int fc = 0; fc < 4; ++fc) {
      const int row = m0 + wm * 64 + mi * 16 + g4 * 4;
      const int col = n0 + wn * 64 + fc * 16 + l16;
      #pragma unroll
      for (int r = 0; r < 4; ++r)
        Cmat[(size_t)(row + r) * N + col] = acc[mi][fc][r];
    }
  }
}

// ---------------- fused RoPE + RMSNorm, Q and K heads in ONE dispatch --------
// grid 4096*20 blocks: hh<16 -> Q head hh (scale (1/sqrt(D))*log2e);
// hh>=16 -> K head hh-16 (scale 1).  Row math identical to rope_norm.
__global__ __launch_bounds__(128)
void rope_norm_all(const unsigned short* __restrict__ QKV, int rstride,
                   const float* __restrict__ Cos, const float* __restrict__ Sin,
                   unsigned short* __restrict__ Qn, unsigned short* __restrict__ Kn) {
  const int idx = blockIdx.x;
  const int hh = idx % 20;
  const int bt = idx / 20;
  const int t  = bt & (T_ - 1);
  const int b  = bt >> 11;
  const int d  = threadIdx.x;        // 0..127
  const bool isQ = hh < 16;
  const int h   = isQ ? hh : hh - 16;
  const int Hn  = isQ ? H_ : HKV_;
  const int col = isQ ? h * D_ : 2048 + h * D_;
  const float out_scale = isQ ? 0.1275174324f : 1.0f;
  unsigned short* Out = isQ ? Qn : Kn;

  const unsigned short* src = QKV + (size_t)bt * rstride + col;
  float y;
  if (d < 64) {
    float x1 = b2f(src[d]), x2 = b2f(src[d + 64]);
    float c = Cos[t * 64 + d], s = Sin[t * 64 + d];
    y = x1 * c + x2 * s;
  } else {
    int dd = d - 64;
    float x1 = b2f(src[dd]), x2 = b2f(src[d]);
    float c = Cos[t * 64 + dd], s = Sin[t * 64 + dd];
    y = -x1 * s + x2 * c;
  }
  float ss = y * y;
  #pragma unroll
  for (int m = 32; m; m >>= 1) ss += __shfl_xor(ss, m);
  __shared__ float red[2];
  if ((d & 63) == 0) red[d >> 6] = ss;
  __syncthreads();
  const float tot  = red[0] + red[1];
  const float rinv = rsqrtf(tot * (1.0f / 128.0f) + 1.1920929e-7f) * out_scale;
  Out[(((size_t)b * Hn + h) * T_ + t) * D_ + d] = f2b(y * rinv);
}

// ---------------- V: [B,T,*,D] bf16 (strided) -> [B,HKV,D,T] bf16 ------------
__global__ __launch_bounds__(256)
void vtrans(const unsigned short* __restrict__ Vf, int rstride,
            unsigned short* __restrict__ Vt) {
  __shared__ float tile[32][65];
  const int t0 = blockIdx.x * 64;
  const int d0 = blockIdx.y * 32;
  const int bh = blockIdx.z;
  const int b = bh >> 2, hk = bh & 3;
  const int tid = threadIdx.x;
  {
    const int di = tid & 31, ts = tid >> 5;
    #pragma unroll
    for (int i = 0; i < 8; ++i) {
      int tt = ts + i * 8;
      tile[di][tt] = b2f(Vf[(size_t)(b * T_ + t0 + tt) * rstride + hk * D_ + d0 + di]);
    }
  }
  __syncthreads();
  {
    const int ti = tid & 63, ds = tid >> 6;
    #pragma unroll
    for (int i = 0; i < 8; ++i) {
      int dd = ds * 8 + i;
      Vt[((size_t)bh * D_ + d0 + dd) * T_ + t0 + ti] = f2b(tile[dd][ti]);
    }
  }
}

// ---------------- flash attention, causal, 8-wave / KVB=128 ------------------
// R15-validated version (59.4 us): split grid (32 bh x 16), complementary qt
// map, &15 swizzle (conflict-free), in-register P, fixed-shift softmax.
#define KVB 128

__global__ __launch_bounds__(512)
void attn_kernel(const unsigned short* __restrict__ Qn,
                 const unsigned short* __restrict__ Kn,
                 const unsigned short* __restrict__ Vt,
                 unsigned short* __restrict__ Yb) {
  __shared__ alignas(16) unsigned short Ks[2][KVB][D_];   // [key][chunk^(key&15)]
  __shared__ alignas(16) unsigned short Vs[2][D_][KVB];   // V^T [d][chunk^(d&15)]

  const int tid = threadIdx.x;
  const int lane = tid & 63;
  const int w = tid >> 6;                 // 0..7
  const int wq  = w & 3;                  // q-row group
  const int kvg = w >> 2;                 // kv key group (0: keys 0-63, 1: 64-127)
  const int l31 = lane & 31;
  const int hi  = lane >> 5;
  const int bh = blockIdx.x;              // bh-major: XCD KV working set = 4MB
  const int by = blockIdx.y;
  const int qt = (by < 8) ? by : 23 - by; // complementary halves
  const int b = bh >> 4, h = bh & 15;
  const int hk = h >> 2;                  // GQA: 4 q-heads per kv-head

  const unsigned short* kp = Kn + ((size_t)(b * HKV_ + hk) * T_) * D_;
  const unsigned short* vp = Vt + ((size_t)(b * HKV_ + hk) * D_) * T_;

  // staging lane decomposition: 4 rows (1KB) per gl16, 16 chunks/row
  const int r4 = lane >> 4, c16 = lane & 15;

  const int t0 = qt * 128;
  const int qrow0 = t0 + wq * 32;
  const int qmax = qrow0 + 31;
  const int nt = qt + 1;
  const int qglob = qrow0 + l31;

  // Q fragments: B-operand, col=q=lane&31, k-chunk = hi*8
  const unsigned short* qp = Qn + ((size_t)bh * T_ + qrow0) * D_;
  bf16x8 qf[8];
  #pragma unroll
  for (int ds = 0; ds < 8; ++ds)
    qf[ds] = *(const bf16x8*)(qp + (size_t)l31 * D_ + ds * 16 + hi * 8);

  f32x16 o[4] = {};        // o[db]: O[q=crow(r,hi)][d = db*32 + l31] (group partial)
  float l_lane = 0.f;      // per-lane partial l for q = l31 over this kv group

  auto stage = [&](int tt) {
    const int buf = tt & 1;
    const int kv = tt * KVB;
    #pragma unroll
    for (int j = 0; j < 4; ++j) {
      const int row = w * 16 + j * 4 + r4;
      const int cg = c16 ^ (row & 15);
      gl16(kp + (size_t)(kv + row) * D_ + cg * 8, &Ks[buf][w * 16 + j * 4][0]);
    }
    #pragma unroll
    for (int j = 0; j < 4; ++j) {
      const int row = w * 16 + j * 4 + r4;   // d row
      const int cg = c16 ^ (row & 15);
      gl16(vp + (size_t)row * T_ + kv + cg * 8, &Vs[buf][w * 16 + j * 4][0]);
    }
  };

  stage(0);   // prologue

  union PAu { unsigned u[4]; bf16x8 v; };

  for (int t = 0; t < nt; ++t) {
    __syncthreads();          // drains vmcnt(0): buf[t&1] staged; prev reads done
    if (t + 1 < nt) stage(t + 1);
    const int kbase = t * KVB + kvg * 64;   // this wave's key base
    if (kbase <= qmax) {
      const unsigned short (*kb)[D_]  = Ks[t & 1];
      const unsigned short (*vbp)[KVB] = Vs[t & 1];
      // ---- QK^T swapped: mfma32(K_frag, Q_frag) over this wave's 64 keys ----
      f32x16 s0 = {}, s1 = {};
      __builtin_amdgcn_s_setprio(1);
      #pragma unroll
      for (int ds = 0; ds < 8; ++ds) {
        const int key0 = kvg * 64 + l31;
        const int key1 = kvg * 64 + 32 + l31;
        bf16x8 k0 = *(const bf16x8*)&kb[key0][(((ds * 2 + hi) ^ (key0 & 15)) << 3)];
        bf16x8 k1 = *(const bf16x8*)&kb[key1][(((ds * 2 + hi) ^ (key1 & 15)) << 3)];
        s0 = __builtin_amdgcn_mfma_f32_32x32x16_bf16(k0, qf[ds], s0, 0, 0, 0);
        s1 = __builtin_amdgcn_mfma_f32_32x32x16_bf16(k1, qf[ds], s1, 0, 0, 0);
      }
      __builtin_amdgcn_s_setprio(0);
      // ---- softmax (fixed-shift, exp2 domain; RMSNorm bound |arg|<=16.33) ----
      const bool need_mask = (kbase + 63 > qrow0);
      float e0[16], e1[16];
      float ls = 0.f;
      #pragma unroll
      for (int r = 0; r < 16; ++r) {
        const int crow = (r & 3) + 8 * (r >> 2) + 4 * hi;
        float v0 = EXP2(s0[r]);
        float v1 = EXP2(s1[r]);
        if (need_mask) {
          v0 = (kbase + crow      <= qglob) ? v0 : 0.f;
          v1 = (kbase + 32 + crow <= qglob) ? v1 : 0.f;
        }
        e0[r] = v0; e1[r] = v1;
        ls += v0 + v1;
      }
      l_lane += ls;
      // ---- build PV A-fragments in-register (cvt_pk + permlane32_swap) ----
      PAu pa[4];
      {
        unsigned a0 = cvtpk(e0[0],  e0[1]),  a1 = cvtpk(e0[2],  e0[3]);
        unsigned b0 = cvtpk(e0[4],  e0[5]),  b1 = cvtpk(e0[6],  e0[7]);
        unsigned c0 = cvtpk(e0[8],  e0[9]),  c1 = cvtpk(e0[10], e0[11]);
        unsigned d0 = cvtpk(e0[12], e0[13]), d1 = cvtpk(e0[14], e0[15]);
        pl32(a0, b0); pl32(a1, b1); pl32(c0, d0); pl32(c1, d1);
        pa[0].u[0] = a0; pa[0].u[1] = a1; pa[0].u[2] = b0; pa[0].u[3] = b1;
        pa[1].u[0] = c0; pa[1].u[1] = c1; pa[1].u[2] = d0; pa[1].u[3] = d1;
      }
      {
        unsigned a0 = cvtpk(e1[0],  e1[1]),  a1 = cvtpk(e1[2],  e1[3]);
        unsigned b0 = cvtpk(e1[4],  e1[5]),  b1 = cvtpk(e1[6],  e1[7]);
        unsigned c0 = cvtpk(e1[8],  e1[9]),  c1 = cvtpk(e1[10], e1[11]);
        unsigned d0 = cvtpk(e1[12], e1[13]), d1 = cvtpk(e1[14], e1[15]);
        pl32(a0, b0); pl32(a1, b1); pl32(c0, d0); pl32(c1, d1);
        pa[2].u[0] = a0; pa[2].u[1] = a1; pa[2].u[2] = b0; pa[2].u[3] = b1;
        pa[3].u[0] = c0; pa[3].u[1] = c1; pa[3].u[2] = d0; pa[3].u[3] = d1;
      }
      // ---- PV: O[q][d] += P[q][key] * V[key][d], V as B-frag from V^T ----
      __builtin_amdgcn_s_setprio(1);
      #pragma unroll
      for (int ks = 0; ks < 4; ++ks) {
        #pragma unroll
        for (int db = 0; db < 4; ++db) {
          const int d = db * 32 + l31;
          const int c = (kvg * 8 + ks * 2 + hi) ^ (d & 15);
          bf16x8 vf = *(const bf16x8*)&vbp[d][c << 3];
          o[db] = __builtin_amdgcn_mfma_f32_32x32x16_bf16(pa[ks].v, vf, o[db], 0, 0, 0);
        }
      }
      __builtin_amdgcn_s_setprio(0);
    }
  }

  // ---- epilogue: combine kv-group partials via LDS (reuse K/V buffers) ----
  const float lfull = l_lane + __shfl_xor(l_lane, 32);  // this group's l for q=l31
  __syncthreads();                       // all waves done with K/V LDS
  float* obuf = (float*)&Ks[0][0][0];    // 64 KB: 4 waves x 4096 floats
  float* lbuf = (float*)&Vs[0][0][0];
  if (w >= 4) {
    const int base = (w - 4) * 4096;
    #pragma unroll
    for (int r = 0; r < 16; ++r)
      #pragma unroll
      for (int db = 0; db < 4; ++db)
        obuf[base + (r * 4 + db) * 64 + lane] = o[db][r];
    if (hi == 0) lbuf[(w - 4) * 32 + l31] = lfull;
  }
  __syncthreads();
  if (w < 4) {
    const int base = w * 4096;
    const float ltot = lfull + lbuf[w * 32 + l31];
    const float invq = 1.0f / ltot;
    #pragma unroll
    for (int r = 0; r < 16; ++r) {
      const int crow = (r & 3) + 8 * (r >> 2) + 4 * hi;
      const float inv = __shfl(invq, crow);
      unsigned short* yrow = Yb + ((size_t)(b * T_ + qrow0 + crow) * CEMB) + h * D_;
      #pragma unroll
      for (int db = 0; db < 4; ++db)
        yrow[db * 32 + l31] = f2b((o[db][r] + obuf[base + (r * 4 + db) * 64 + lane]) * inv);
    }
  }
}

// ---------------------------------------------------------------------------
extern "C" void kernel_launch(void* const* d_in, const int* in_sizes, int n_in,
                              void* d_out, int out_size, void* d_ws, size_t ws_size,
                              hipStream_t stream) {
  const float* x    = (const float*)d_in[0];
  const float* cosp = (const float*)d_in[1];
  const float* sinp = (const float*)d_in[2];
  const float* Wq   = (const float*)d_in[3];
  const float* Wk   = (const float*)d_in[4];
  const float* Wv   = (const float*)d_in[5];
  const float* Wo   = (const float*)d_in[6];
  float* out = (float*)d_out;

  char* ws = (char*)d_ws;
  size_t off = 0;
  auto alloc = [&](size_t bytes) {
    void* p = ws + off;
    off += (bytes + 255) & ~(size_t)255;
    return p;
  };
  const size_t MT = (size_t)B_ * T_;  // 4096
  const int NQKV = 3072;              // 2048 q + 512 k + 512 v
  unsigned short* xb    = (unsigned short*)alloc(MT * CEMB * 2);
  unsigned short* wqkvb = (unsigned short*)alloc((size_t)NQKV * 2048 * 2);
  unsigned short* wob   = (unsigned short*)alloc((size_t)2048 * 2048 * 2);
  unsigned short* qkvb  = (unsigned short*)alloc(MT * NQKV * 2);
  unsigned short* qn    = (unsigned short*)alloc((size_t)B_ * H_ * T_ * D_ * 2);
  unsigned short* kn    = (unsigned short*)alloc((size_t)B_ * HKV_ * T_ * D_ * 2);
  unsigned short* vt    = (unsigned short*)alloc((size_t)B_ * HKV_ * D_ * T_ * 2);
  unsigned short* yb    = (unsigned short*)alloc(MT * CEMB * 2);

  // all 5 f32->bf16 conversions in ONE dispatch
  cvt_multi<<<2048, 256, 0, stream>>>(
      x,  xb,                  (int)(MT * CEMB / 4),
      Wq, wqkvb,               2048 * 2048 / 4,
      Wk, wqkvb + 2048 * 2048, 512 * 2048 / 4,
      Wv, wqkvb + 2560 * 2048, 512 * 2048 / 4,
      Wo, wob,                 1024 * 4096 / 4);

  // fused QKV projection: [4096][3072] bf16  (grid 16x16 = 256 blocks, full)
  gemm_n192<<<dim3(NQKV / 192, 4096 / 256), 512, 0, stream>>>(xb, wqkvb, qkvb, 4096, NQKV, 2048);

  // RoPE + RMSNorm for Q and K heads in one dispatch
  rope_norm_all<<<4096 * 20, 128, 0, stream>>>(qkvb, NQKV, cosp, sinp, qn, kn);
  vtrans<<<dim3(T_ / 64, D_ / 32, B_ * HKV_), 256, 0, stream>>>(qkvb + 2560, NQKV, vt);

  // causal flash attention: split grid (32 x 16), complementary qt map
  attn_kernel<<<dim3(B_ * H_, 16), 512, 0, stream>>>(qn, kn, vt, yb);

  // output projection -> f32 d_out  (grid 16x16 = 256 blocks, full machine)
  gemm_n128<<<dim3(2048 / 128, 4096 / 256), 512, 0, stream>>>(yb, wob, out, 4096, 2048, 2048);
}

// Round 20
// 186.416 us; speedup vs baseline: 1.0211x; 1.0049x over previous
//
#include <hip/hip_runtime.h>
#include <hip/hip_bf16.h>
#include <stdint.h>

#define B_   2
#define T_   2048
#define CEMB 2048
#define H_   16
#define HKV_ 4
#define D_   128

typedef __attribute__((ext_vector_type(8))) short bf16x8;    // 8 x bf16 (4 VGPR)
typedef __attribute__((ext_vector_type(4))) float f32x4;     // 16x16 MFMA acc
typedef __attribute__((ext_vector_type(16))) float f32x16;   // 32x32 MFMA acc

#if __has_builtin(__builtin_amdgcn_exp2f)
#define EXP2(x) __builtin_amdgcn_exp2f(x)
#else
#define EXP2(x) exp2f(x)
#endif

__device__ __forceinline__ unsigned short f2b(float f) {
  union { float f; unsigned u; } v; v.f = f;
  unsigned r = v.u + 0x7FFFu + ((v.u >> 16) & 1u);   // RNE
  return (unsigned short)(r >> 16);
}
__device__ __forceinline__ float b2f(unsigned short u) {
  union { unsigned u; float f; } v; v.u = ((unsigned)u) << 16; return v.f;
}
// pack 2 f32 -> 2 bf16 (RNE), single instruction; src0 -> low half
__device__ __forceinline__ unsigned cvtpk(float lo, float hi) {
  unsigned r;
  asm("v_cvt_pk_bf16_f32 %0, %1, %2" : "=v"(r) : "v"(lo), "v"(hi));
  return r;
}

// permlane32_swap: a' = [a_lo31 | b_lo31], b' = [a_hi31 | b_hi31]
#if __has_builtin(__builtin_amdgcn_permlane32_swap)
__device__ __forceinline__ void pl32(unsigned& a, unsigned& b) {
  auto r = __builtin_amdgcn_permlane32_swap(a, b, false, false);
  a = r[0]; b = r[1];
}
#else
__device__ __forceinline__ void pl32(unsigned& a, unsigned& b) {
  const bool hih = (threadIdx.x & 32) != 0;
  unsigned sa = __shfl_xor(a, 32), sb = __shfl_xor(b, 32);
  unsigned na = hih ? sb : a;
  unsigned nb = hih ? b : sa;
  a = na; b = nb;
}
#endif

// async global->LDS, 16B per lane; LDS dest = wave-uniform base + lane*16
__device__ __forceinline__ void gl16(const void* g, void* l) {
  __builtin_amdgcn_global_load_lds(
      (const __attribute__((address_space(1))) unsigned int*)g,
      (__attribute__((address_space(3))) unsigned int*)l, 16, 0, 0);
}

#define FENCE() asm volatile("" ::: "memory")

// ---------------- f32 -> bf16 convert, 5 ranges in ONE dispatch --------------
__global__ void cvt_multi(const float* __restrict__ s0, unsigned short* __restrict__ d0, int n0,
                          const float* __restrict__ s1, unsigned short* __restrict__ d1, int n1,
                          const float* __restrict__ s2, unsigned short* __restrict__ d2, int n2,
                          const float* __restrict__ s3, unsigned short* __restrict__ d3, int n3,
                          const float* __restrict__ s4, unsigned short* __restrict__ d4, int n4c) {
  const int stride = gridDim.x * blockDim.x;
  const int t0 = blockIdx.x * blockDim.x + threadIdx.x;
  auto run = [&](const float* __restrict__ s, unsigned short* __restrict__ d, int n) {
    for (int i = t0; i < n; i += stride) {
      float4 v = ((const float4*)s)[i];
      ushort4 o;
      o.x = f2b(v.x); o.y = f2b(v.y); o.z = f2b(v.z); o.w = f2b(v.w);
      ((ushort4*)d)[i] = o;
    }
  };
  run(s0, d0, n0); run(s1, d1, n1); run(s2, d2, n2);
  run(s3, d3, n3); run(s4, d4, n4c);
}

// ---------------- GEMM 256x192 (QKV), single-phase, full-grid ----------------
// (validated R15 structure, unchanged)
__global__ __launch_bounds__(512, 2)
void gemm_n192(const unsigned short* __restrict__ A,
               const unsigned short* __restrict__ W,
               unsigned short* __restrict__ Cmat, int M, int N, int K) {
  __shared__ alignas(16) unsigned short As[2][2][128][64];
  __shared__ alignas(16) unsigned short Bs[2][192][64];

  const int tid  = threadIdx.x;
  const int lane = tid & 63;
  const int w    = tid >> 6;         // wave 0..7
  const int wm   = w >> 1;           // M group: rows wm*64 .. +63
  const int wn   = w & 1;            // N group: cols wn*96 .. +95
  const int l16  = lane & 15, g4 = lane >> 4;
  const int srow = lane >> 3;
  const int schk = lane & 7;

  const int gx  = gridDim.x;         // N/192 = 16
  const int nwg = gx * gridDim.y;
  const int lin = blockIdx.y * gx + blockIdx.x;
  const int cpx = nwg >> 3;
  const int swz = (lin & 7) * cpx + (lin >> 3);
  const int m0 = (swz / gx) * 256;
  const int n0 = (swz % gx) * 192;

  const unsigned short* Ap = A + (size_t)m0 * K;
  const unsigned short* Wp = W + (size_t)n0 * K;
  const int nk = K >> 6;

  const int hA  = wm >> 1;           // this wave's A half
  const int ra0 = (wm & 1) * 64;     // row base within half

  f32x4 acc[4][6] = {};

  auto stA = [&](int ts, int h) {    // A half-tile: 128 rows x 64 k, 2 gl16
    const unsigned short* g = Ap + (size_t)(h * 128 + w * 8 + srow) * K
                                 + ts * 64 + ((schk ^ srow) << 3);
    unsigned short* l = &As[ts & 1][h][w * 8][0];
    gl16(g, l);
    gl16(g + (size_t)64 * K, l + 64 * 64);
  };
  auto stB = [&](int ts, int j) {    // B sub-tile j: 64 rows x 64 k, 1 gl16
    const unsigned short* g = Wp + (size_t)(j * 64 + w * 8 + srow) * K
                                 + ts * 64 + ((schk ^ srow) << 3);
    gl16(g, &Bs[ts & 1][j * 64 + w * 8][0]);
  };

  // prologue: stage tile0 fully (7 gl16/wave), drain, barrier
  stA(0, 0); stA(0, 1); stB(0, 0); stB(0, 1); stB(0, 2);
  asm volatile("s_waitcnt vmcnt(0)" ::: "memory");
  __builtin_amdgcn_s_barrier();
  FENCE();

  for (int t = 0; t < nk; ++t) {
    const int buf = t & 1;
    bf16x8 af[4][2], bfr[6][2];
    #pragma unroll
    for (int mi = 0; mi < 4; ++mi) {
      const int ar = ra0 + mi * 16 + l16;
      #pragma unroll
      for (int ks = 0; ks < 2; ++ks)
        af[mi][ks] = *(const bf16x8*)&As[buf][hA][ar][((ks * 4 + g4) ^ (l16 & 7)) << 3];
    }
    #pragma unroll
    for (int fc = 0; fc < 6; ++fc) {
      const int br = wn * 96 + fc * 16 + l16;
      #pragma unroll
      for (int ks = 0; ks < 2; ++ks)
        bfr[fc][ks] = *(const bf16x8*)&Bs[buf][br][((ks * 4 + g4) ^ (l16 & 7)) << 3];
    }
    if (t + 1 < nk) {
      stA(t + 1, 0); stA(t + 1, 1);
      stB(t + 1, 0); stB(t + 1, 1); stB(t + 1, 2);
    }
    __builtin_amdgcn_s_setprio(1);
    #pragma unroll
    for (int mi = 0; mi < 4; ++mi) {
      #pragma unroll
      for (int fc = 0; fc < 6; ++fc) {
        f32x4 a = acc[mi][fc];
        a = __builtin_amdgcn_mfma_f32_16x16x32_bf16(af[mi][0], bfr[fc][0], a, 0, 0, 0);
        a = __builtin_amdgcn_mfma_f32_16x16x32_bf16(af[mi][1], bfr[fc][1], a, 0, 0, 0);
        acc[mi][fc] = a;
      }
    }
    __builtin_amdgcn_s_setprio(0);
    asm volatile("s_waitcnt vmcnt(0)" ::: "memory");   // t+1 staged (drained under MFMA)
    __builtin_amdgcn_s_barrier();
    FENCE();
  }

  // epilogue: bf16 out
  #pragma unroll
  for (int mi = 0; mi < 4; ++mi) {
    #pragma unroll
    for (int fc = 0; fc < 6; ++fc) {
      const int row = m0 + wm * 64 + mi * 16 + g4 * 4;
      const int col = n0 + wn * 96 + fc * 16 + l16;
      #pragma unroll
      for (int r = 0; r < 4; ++r)
        Cmat[(size_t)(row + r) * N + col] = f2b(acc[mi][fc][r]);
    }
  }
}

// ---------------- GEMM 256x128 (out-proj), single-phase, full-grid -----------
// (validated R15/R17 2-buffer structure)
__global__ __launch_bounds__(512, 2)
void gemm_n128(const unsigned short* __restrict__ A,
               const unsigned short* __restrict__ W,
               float* __restrict__ Cmat, int M, int N, int K) {
  __shared__ alignas(16) unsigned short As[2][2][128][64];
  __shared__ alignas(16) unsigned short Bs[2][2][64][64];

  const int tid  = threadIdx.x;
  const int lane = tid & 63;
  const int w    = tid >> 6;         // wave 0..7
  const int wm   = w >> 1;           // M group: rows wm*64 .. +63
  const int wn   = w & 1;            // N group: cols wn*64 .. +63
  const int l16  = lane & 15, g4 = lane >> 4;
  const int srow = lane >> 3;
  const int schk = lane & 7;

  const int gx  = gridDim.x;         // N/128
  const int nwg = gx * gridDim.y;
  const int lin = blockIdx.y * gx + blockIdx.x;
  const int cpx = nwg >> 3;
  const int swz = (lin & 7) * cpx + (lin >> 3);
  const int m0 = (swz / gx) * 256;
  const int n0 = (swz % gx) * 128;

  const unsigned short* Ap = A + (size_t)m0 * K;
  const unsigned short* Wp = W + (size_t)n0 * K;
  const int nk = K >> 6;

  const int hA  = wm >> 1;
  const int ra0 = (wm & 1) * 64;

  f32x4 acc[4][4] = {};

  auto stA = [&](int ts, int h) {    // A half-tile: 128 rows x 64 k, 2 gl16
    const unsigned short* g = Ap + (size_t)(h * 128 + w * 8 + srow) * K
                                 + ts * 64 + ((schk ^ srow) << 3);
    unsigned short* l = &As[ts & 1][h][w * 8][0];
    gl16(g, l);
    gl16(g + (size_t)64 * K, l + 64 * 64);
  };
  auto stB = [&](int ts, int h) {    // B half-tile: 64 rows x 64 k, 1 gl16
    const unsigned short* g = Wp + (size_t)(h * 64 + w * 8 + srow) * K
                                 + ts * 64 + ((schk ^ srow) << 3);
    gl16(g, &Bs[ts & 1][h][w * 8][0]);
  };

  // prologue
  stA(0, 0); stA(0, 1); stB(0, 0); stB(0, 1);
  asm volatile("s_waitcnt vmcnt(0)" ::: "memory");
  __builtin_amdgcn_s_barrier();
  FENCE();

  for (int t = 0; t < nk; ++t) {
    const int buf = t & 1;
    bf16x8 af[4][2], bfr[4][2];
    #pragma unroll
    for (int mi = 0; mi < 4; ++mi) {
      const int ar = ra0 + mi * 16 + l16;
      #pragma unroll
      for (int ks = 0; ks < 2; ++ks)
        af[mi][ks] = *(const bf16x8*)&As[buf][hA][ar][((ks * 4 + g4) ^ (l16 & 7)) << 3];
    }
    #pragma unroll
    for (int fc = 0; fc < 4; ++fc) {
      const int br = wn * 64 + fc * 16 + l16;   // 0..127 across halves
      const int hb = br >> 6, rb = br & 63;
      #pragma unroll
      for (int ks = 0; ks < 2; ++ks)
        bfr[fc][ks] = *(const bf16x8*)&Bs[buf][hb][rb][((ks * 4 + g4) ^ (l16 & 7)) << 3];
    }
    if (t + 1 < nk) {
      stA(t + 1, 0); stA(t + 1, 1);
      stB(t + 1, 0); stB(t + 1, 1);
    }
    __builtin_amdgcn_s_setprio(1);
    #pragma unroll
    for (int mi = 0; mi < 4; ++mi) {
      #pragma unroll
      for (int fc = 0; fc < 4; ++fc) {
        f32x4 a = acc[mi][fc];
        a = __builtin_amdgcn_mfma_f32_16x16x32_bf16(af[mi][0], bfr[fc][0], a, 0, 0, 0);
        a = __builtin_amdgcn_mfma_f32_16x16x32_bf16(af[mi][1], bfr[fc][1], a, 0, 0, 0);
        acc[mi][fc] = a;
      }
    }
    __builtin_amdgcn_s_setprio(0);
    asm volatile("s_waitcnt vmcnt(0)" ::: "memory");
    __builtin_amdgcn_s_barrier();
    FENCE();
  }

  // epilogue: f32 out
  #pragma unroll
  for (int mi = 0; mi < 4; ++mi) {
    #pragma unroll
    for (int fc = 0; fc < 4; ++fc) {
      const int row = m0 + wm * 64 + mi * 16 + g4 * 4;
      const int col = n0 + wn * 64 + fc * 16 + l16;
      #pragma unroll
      for (int r = 0; r < 4; ++r)
        Cmat[(size_t)(row + r) * N + col] = acc[mi][fc][r];
    }
  }
}

// ---------------- fused RoPE + RMSNorm, Q and K heads in ONE dispatch --------
__global__ __launch_bounds__(128)
void rope_norm_all(const unsigned short* __restrict__ QKV, int rstride,
                   const float* __restrict__ Cos, const float* __restrict__ Sin,
                   unsigned short* __restrict__ Qn, unsigned short* __restrict__ Kn) {
  const int idx = blockIdx.x;
  const int hh = idx % 20;
  const int bt = idx / 20;
  const int t  = bt & (T_ - 1);
  const int b  = bt >> 11;
  const int d  = threadIdx.x;        // 0..127
  const bool isQ = hh < 16;
  const int h   = isQ ? hh : hh - 16;
  const int Hn  = isQ ? H_ : HKV_;
  const int col = isQ ? h * D_ : 2048 + h * D_;
  const float out_scale = isQ ? 0.1275174324f : 1.0f;
  unsigned short* Out = isQ ? Qn : Kn;

  const unsigned short* src = QKV + (size_t)bt * rstride + col;
  float y;
  if (d < 64) {
    float x1 = b2f(src[d]), x2 = b2f(src[d + 64]);
    float c = Cos[t * 64 + d], s = Sin[t * 64 + d];
    y = x1 * c + x2 * s;
  } else {
    int dd = d - 64;
    float x1 = b2f(src[dd]), x2 = b2f(src[d]);
    float c = Cos[t * 64 + dd], s = Sin[t * 64 + dd];
    y = -x1 * s + x2 * c;
  }
  float ss = y * y;
  #pragma unroll
  for (int m = 32; m; m >>= 1) ss += __shfl_xor(ss, m);
  __shared__ float red[2];
  if ((d & 63) == 0) red[d >> 6] = ss;
  __syncthreads();
  const float tot  = red[0] + red[1];
  const float rinv = rsqrtf(tot * (1.0f / 128.0f) + 1.1920929e-7f) * out_scale;
  Out[(((size_t)b * Hn + h) * T_ + t) * D_ + d] = f2b(y * rinv);
}

// ---------------- V: [B,T,*,D] bf16 (strided) -> [B,HKV,D,T] bf16 ------------
__global__ __launch_bounds__(256)
void vtrans(const unsigned short* __restrict__ Vf, int rstride,
            unsigned short* __restrict__ Vt) {
  __shared__ float tile[32][65];
  const int t0 = blockIdx.x * 64;
  const int d0 = blockIdx.y * 32;
  const int bh = blockIdx.z;
  const int b = bh >> 2, hk = bh & 3;
  const int tid = threadIdx.x;
  {
    const int di = tid & 31, ts = tid >> 5;
    #pragma unroll
    for (int i = 0; i < 8; ++i) {
      int tt = ts + i * 8;
      tile[di][tt] = b2f(Vf[(size_t)(b * T_ + t0 + tt) * rstride + hk * D_ + d0 + di]);
    }
  }
  __syncthreads();
  {
    const int ti = tid & 63, ds = tid >> 6;
    #pragma unroll
    for (int i = 0; i < 8; ++i) {
      int dd = ds * 8 + i;
      Vt[((size_t)bh * D_ + d0 + dd) * T_ + t0 + ti] = f2b(tile[dd][ti]);
    }
  }
}

// ---------------- flash attention, causal, 8-wave / KVB=128 ------------------
// R15 structure + XCD-aware block remap: lin&7 -> (b,hk), so each XCD's 64
// blocks share ONE kv-head's K/V (1 MB) + 4 q-heads' Q (2 MB) = L2-resident.
// Stage drains become L2 hits instead of HBM misses.
#define KVB 128

__global__ __launch_bounds__(512)
void attn_kernel(const unsigned short* __restrict__ Qn,
                 const unsigned short* __restrict__ Kn,
                 const unsigned short* __restrict__ Vt,
                 unsigned short* __restrict__ Yb) {
  __shared__ alignas(16) unsigned short Ks[2][KVB][D_];   // [key][chunk^(key&15)]
  __shared__ alignas(16) unsigned short Vs[2][D_][KVB];   // V^T [d][chunk^(d&15)]

  const int tid = threadIdx.x;
  const int lane = tid & 63;
  const int w = tid >> 6;                 // 0..7
  const int wq  = w & 3;                  // q-row group
  const int kvg = w >> 2;                 // kv key group (0: keys 0-63, 1: 64-127)
  const int l31 = lane & 31;
  const int hi  = lane >> 5;

  // XCD-aware remap: lin&7 = b*4+hk -> all blocks of one (b,hk) on one XCD
  const int lin = blockIdx.y * gridDim.x + blockIdx.x;    // 0..511
  const int xcd = lin & 7;
  const int rest = lin >> 3;              // 0..63
  const int b  = xcd >> 2;
  const int hk = xcd & 3;
  const int hl = rest & 3;
  const int by = rest >> 2;               // 0..15
  const int h  = hk * 4 + hl;
  const int bh = b * 16 + h;
  const int qt = (by < 8) ? by : 23 - by; // complementary halves

  const unsigned short* kp = Kn + ((size_t)(b * HKV_ + hk) * T_) * D_;
  const unsigned short* vp = Vt + ((size_t)(b * HKV_ + hk) * D_) * T_;

  // staging lane decomposition: 4 rows (1KB) per gl16, 16 chunks/row
  const int r4 = lane >> 4, c16 = lane & 15;

  const int t0 = qt * 128;
  const int qrow0 = t0 + wq * 32;
  const int qmax = qrow0 + 31;
  const int nt = qt + 1;
  const int qglob = qrow0 + l31;

  // Q fragments: B-operand, col=q=lane&31, k-chunk = hi*8
  const unsigned short* qp = Qn + ((size_t)bh * T_ + qrow0) * D_;
  bf16x8 qf[8];
  #pragma unroll
  for (int ds = 0; ds < 8; ++ds)
    qf[ds] = *(const bf16x8*)(qp + (size_t)l31 * D_ + ds * 16 + hi * 8);

  f32x16 o[4] = {};        // o[db]: O[q=crow(r,hi)][d = db*32 + l31] (group partial)
  float l_lane = 0.f;      // per-lane partial l for q = l31 over this kv group

  auto stage = [&](int tt) {
    const int buf = tt & 1;
    const int kv = tt * KVB;
    #pragma unroll
    for (int j = 0; j < 4; ++j) {
      const int row = w * 16 + j * 4 + r4;
      const int cg = c16 ^ (row & 15);
      gl16(kp + (size_t)(kv + row) * D_ + cg * 8, &Ks[buf][w * 16 + j * 4][0]);
    }
    #pragma unroll
    for (int j = 0; j < 4; ++j) {
      const int row = w * 16 + j * 4 + r4;   // d row
      const int cg = c16 ^ (row & 15);
      gl16(vp + (size_t)row * T_ + kv + cg * 8, &Vs[buf][w * 16 + j * 4][0]);
    }
  };

  stage(0);   // prologue

  union PAu { unsigned u[4]; bf16x8 v; };

  for (int t = 0; t < nt; ++t) {
    __syncthreads();          // drains vmcnt(0): buf[t&1] staged; prev reads done
    if (t + 1 < nt) stage(t + 1);
    const int kbase = t * KVB + kvg * 64;   // this wave's key base
    if (kbase <= qmax) {
      const unsigned short (*kb)[D_]  = Ks[t & 1];
      const unsigned short (*vbp)[KVB] = Vs[t & 1];
      // ---- QK^T swapped: mfma32(K_frag, Q_frag) over this wave's 64 keys ----
      f32x16 s0 = {}, s1 = {};
      __builtin_amdgcn_s_setprio(1);
      #pragma unroll
      for (int ds = 0; ds < 8; ++ds) {
        const int key0 = kvg * 64 + l31;
        const int key1 = kvg * 64 + 32 + l31;
        bf16x8 k0 = *(const bf16x8*)&kb[key0][(((ds * 2 + hi) ^ (key0 & 15)) << 3)];
        bf16x8 k1 = *(const bf16x8*)&kb[key1][(((ds * 2 + hi) ^ (key1 & 15)) << 3)];
        s0 = __builtin_amdgcn_mfma_f32_32x32x16_bf16(k0, qf[ds], s0, 0, 0, 0);
        s1 = __builtin_amdgcn_mfma_f32_32x32x16_bf16(k1, qf[ds], s1, 0, 0, 0);
      }
      __builtin_amdgcn_s_setprio(0);
      // ---- softmax (fixed-shift, exp2 domain; RMSNorm bound |arg|<=16.33) ----
      const bool need_mask = (kbase + 63 > qrow0);
      float e0[16], e1[16];
      float ls = 0.f;
      #pragma unroll
      for (int r = 0; r < 16; ++r) {
        const int crow = (r & 3) + 8 * (r >> 2) + 4 * hi;
        float v0 = EXP2(s0[r]);
        float v1 = EXP2(s1[r]);
        if (need_mask) {
          v0 = (kbase + crow      <= qglob) ? v0 : 0.f;
          v1 = (kbase + 32 + crow <= qglob) ? v1 : 0.f;
        }
        e0[r] = v0; e1[r] = v1;
        ls += v0 + v1;
      }
      l_lane += ls;
      // ---- build PV A-fragments in-register (cvt_pk + permlane32_swap) ----
      PAu pa[4];
      {
        unsigned a0 = cvtpk(e0[0],  e0[1]),  a1 = cvtpk(e0[2],  e0[3]);
        unsigned b0 = cvtpk(e0[4],  e0[5]),  b1 = cvtpk(e0[6],  e0[7]);
        unsigned c0 = cvtpk(e0[8],  e0[9]),  c1 = cvtpk(e0[10], e0[11]);
        unsigned d0 = cvtpk(e0[12], e0[13]), d1 = cvtpk(e0[14], e0[15]);
        pl32(a0, b0); pl32(a1, b1); pl32(c0, d0); pl32(c1, d1);
        pa[0].u[0] = a0; pa[0].u[1] = a1; pa[0].u[2] = b0; pa[0].u[3] = b1;
        pa[1].u[0] = c0; pa[1].u[1] = c1; pa[1].u[2] = d0; pa[1].u[3] = d1;
      }
      {
        unsigned a0 = cvtpk(e1[0],  e1[1]),  a1 = cvtpk(e1[2],  e1[3]);
        unsigned b0 = cvtpk(e1[4],  e1[5]),  b1 = cvtpk(e1[6],  e1[7]);
        unsigned c0 = cvtpk(e1[8],  e1[9]),  c1 = cvtpk(e1[10], e1[11]);
        unsigned d0 = cvtpk(e1[12], e1[13]), d1 = cvtpk(e1[14], e1[15]);
        pl32(a0, b0); pl32(a1, b1); pl32(c0, d0); pl32(c1, d1);
        pa[2].u[0] = a0; pa[2].u[1] = a1; pa[2].u[2] = b0; pa[2].u[3] = b1;
        pa[3].u[0] = c0; pa[3].u[1] = c1; pa[3].u[2] = d0; pa[3].u[3] = d1;
      }
      // ---- PV: O[q][d] += P[q][key] * V[key][d], V as B-frag from V^T ----
      __builtin_amdgcn_s_setprio(1);
      #pragma unroll
      for (int ks = 0; ks < 4; ++ks) {
        #pragma unroll
        for (int db = 0; db < 4; ++db) {
          const int d = db * 32 + l31;
          const int c = (kvg * 8 + ks * 2 + hi) ^ (d & 15);
          bf16x8 vf = *(const bf16x8*)&vbp[d][c << 3];
          o[db] = __builtin_amdgcn_mfma_f32_32x32x16_bf16(pa[ks].v, vf, o[db], 0, 0, 0);
        }
      }
      __builtin_amdgcn_s_setprio(0);
    }
  }

  // ---- epilogue: combine kv-group partials via LDS (reuse K/V buffers) ----
  const float lfull = l_lane + __shfl_xor(l_lane, 32);  // this group's l for q=l31
  __syncthreads();                       // all waves done with K/V LDS
  float* obuf = (float*)&Ks[0][0][0];    // 64 KB: 4 waves x 4096 floats
  float* lbuf = (float*)&Vs[0][0][0];
  if (w >= 4) {
    const int base = (w - 4) * 4096;
    #pragma unroll
    for (int r = 0; r < 16; ++r)
      #pragma unroll
      for (int db = 0; db < 4; ++db)
        obuf[base + (r * 4 + db) * 64 + lane] = o[db][r];
    if (hi == 0) lbuf[(w - 4) * 32 + l31] = lfull;
  }
  __syncthreads();
  if (w < 4) {
    const int base = w * 4096;
    const float ltot = lfull + lbuf[w * 32 + l31];
    const float invq = 1.0f / ltot;
    #pragma unroll
    for (int r = 0; r < 16; ++r) {
      const int crow = (r & 3) + 8 * (r >> 2) + 4 * hi;
      const float inv = __shfl(invq, crow);
      unsigned short* yrow = Yb + ((size_t)(b * T_ + qrow0 + crow) * CEMB) + h * D_;
      #pragma unroll
      for (int db = 0; db < 4; ++db)
        yrow[db * 32 + l31] = f2b((o[db][r] + obuf[base + (r * 4 + db) * 64 + lane]) * inv);
    }
  }
}

// ---------------------------------------------------------------------------
extern "C" void kernel_launch(void* const* d_in, const int* in_sizes, int n_in,
                              void* d_out, int out_size, void* d_ws, size_t ws_size,
                              hipStream_t stream) {
  const float* x    = (const float*)d_in[0];
  const float* cosp = (const float*)d_in[1];
  const float* sinp = (const float*)d_in[2];
  const float* Wq   = (const float*)d_in[3];
  const float* Wk   = (const float*)d_in[4];
  const float* Wv   = (const float*)d_in[5];
  const float* Wo   = (const float*)d_in[6];
  float* out = (float*)d_out;

  char* ws = (char*)d_ws;
  size_t off = 0;
  auto alloc = [&](size_t bytes) {
    void* p = ws + off;
    off += (bytes + 255) & ~(size_t)255;
    return p;
  };
  const size_t MT = (size_t)B_ * T_;  // 4096
  const int NQKV = 3072;              // 2048 q + 512 k + 512 v
  unsigned short* xb    = (unsigned short*)alloc(MT * CEMB * 2);
  unsigned short* wqkvb = (unsigned short*)alloc((size_t)NQKV * 2048 * 2);
  unsigned short* wob   = (unsigned short*)alloc((size_t)2048 * 2048 * 2);
  unsigned short* qkvb  = (unsigned short*)alloc(MT * NQKV * 2);
  unsigned short* qn    = (unsigned short*)alloc((size_t)B_ * H_ * T_ * D_ * 2);
  unsigned short* kn    = (unsigned short*)alloc((size_t)B_ * HKV_ * T_ * D_ * 2);
  unsigned short* vt    = (unsigned short*)alloc((size_t)B_ * HKV_ * D_ * T_ * 2);
  unsigned short* yb    = (unsigned short*)alloc(MT * CEMB * 2);

  // all 5 f32->bf16 conversions in ONE dispatch
  cvt_multi<<<2048, 256, 0, stream>>>(
      x,  xb,                  (int)(MT * CEMB / 4),
      Wq, wqkvb,               2048 * 2048 / 4,
      Wk, wqkvb + 2048 * 2048, 512 * 2048 / 4,
      Wv, wqkvb + 2560 * 2048, 512 * 2048 / 4,
      Wo, wob,                 1024 * 4096 / 4);

  // fused QKV projection: [4096][3072] bf16  (grid 16x16 = 256 blocks, full)
  gemm_n192<<<dim3(NQKV / 192, 4096 / 256), 512, 0, stream>>>(xb, wqkvb, qkvb, 4096, NQKV, 2048);

  // RoPE + RMSNorm for Q and K heads in one dispatch
  rope_norm_all<<<4096 * 20, 128, 0, stream>>>(qkvb, NQKV, cosp, sinp, qn, kn);
  vtrans<<<dim3(T_ / 64, D_ / 32, B_ * HKV_), 256, 0, stream>>>(qkvb + 2560, NQKV, vt);

  // causal flash attention: XCD-remapped split grid (32 x 16)
  attn_kernel<<<dim3(B_ * H_, 16), 512, 0, stream>>>(qn, kn, vt, yb);

  // output projection -> f32 d_out  (grid 16x16 = 256 blocks, full machine)
  gemm_n128<<<dim3(2048 / 128, 4096 / 256), 512, 0, stream>>>(yb, wob, out, 4096, 2048, 2048);
}